// Round 2
// 294.098 us; speedup vs baseline: 1.8276x; 1.8276x over previous
//
#include <hip/hip_runtime.h>
#include <hip/hip_bf16.h>

#define BF __hip_bfloat16

// B=16, C=64, H=128, W=128, MX=MY=24, HIDDEN=32
// fp32 in/out; intermediates bf16.
//
// Workspace (bf16 units, peak 7471104 units = 14.94 MB):
//   Tr [0,3145728)        [bc][y24][u128]   (dead after k_fft_h)
//   Ti [3145728,6291456)
//   Xr [6291456,6881280)  [xy][bc]          (dead after k_mix)
//   Xi [6881280,7471104)
//   Sr [0,589824)         [bo][xy]   aliases Tr (T dead)
//   Si [589824,1179648)
//   Pr [1179648,4325376)  [bo][u][y] aliases Tr/Ti tail (dead)
//   Pi [4325376,7471104)             aliases Ti/X (X dead after k_mix)
//
// R6: k_fused on MFMA: 537 -> 298 us, but FAILED post-timing replay check
// (first launch correct, warm replays consistently wrong). All index/barrier
// math audited correct; prime suspect is the double LDS aliasing (H1=XT,
// Zl=Plds) + vector ds_read MFMA operands -- the known hipcc hazard class
// (ordering around waits/barriers with aliased LDS).
// R7: SAME MFMA structure, ZERO LDS aliasing:
//   - skip-GEMM A-frags loaded directly from global x (no XT region at all)
//   - Plds / H1 / Zl are three disjoint static __shared__ arrays (37.9 KB)
//   - every LDS region is write-once -> read, protected by one barrier

typedef __attribute__((ext_vector_type(8))) short s8b;    // 8 bf16 (4 VGPRs)
typedef __attribute__((ext_vector_type(4))) float f32x4;  // MFMA acc

__device__ __forceinline__ float geluf(float v) {
    return 0.5f * v * (1.0f + erff(v * 0.7071067811865476f));
}
__device__ __forceinline__ float bf2f(BF v) { return __bfloat162float(v); }
__device__ __forceinline__ short f2bs(float f) {
    union { BF h; short s; } u; u.h = __float2bfloat16(f); return u.s;
}
// build bf16x8 B-fragment from 8 consecutive fp32 (row-major [col][k] weights)
__device__ __forceinline__ s8b ld8f(const float* __restrict__ p) {
    float4 a = *(const float4*)p;
    float4 b = *(const float4*)(p + 4);
    s8b r;
    r[0] = f2bs(a.x); r[1] = f2bs(a.y); r[2] = f2bs(a.z); r[3] = f2bs(a.w);
    r[4] = f2bs(b.x); r[5] = f2bs(b.y); r[6] = f2bs(b.z); r[7] = f2bs(b.w);
    return r;
}

// ---------------------------------------------------------------------------
// k_fft_w: forward DFT along W.  T[bc][y][u] = sum_v x[bc][u][v] e^{-2pi i v y/128}
// Block = (bc, half of rows).  Grid 2048.
// ---------------------------------------------------------------------------
__global__ __launch_bounds__(256) void k_fft_w(const float* __restrict__ x,
                                               BF* __restrict__ TrB,
                                               BF* __restrict__ TiB) {
    __shared__ __align__(16) float xs[64 * 132];
    __shared__ __align__(16) float tcs[24 * 132];
    __shared__ __align__(16) float tss[24 * 132];
    const int tid = threadIdx.x;
    const int bc  = blockIdx.x >> 1;
    const int uh  = (blockIdx.x & 1) << 6;            // 0 or 64

    for (int i = tid; i < 3072; i += 256) {
        int m = i >> 7, a = i & 127;
        int r = (a * m) & 127;
        float th = (float)r * 0.04908738521234052f;   // 2*pi/128
        float s, c; __sincosf(th, &s, &c);
        tcs[m * 132 + a] = c;
        tss[m * 132 + a] = s;
    }
    const float4* xb = (const float4*)(x + ((size_t)bc << 14) + ((size_t)uh << 7));
    for (int i = tid; i < 2048; i += 256) {           // 64 rows * 32 float4
        float4 v = xb[i];
        int row = i >> 5, col = (i & 31) << 2;
        *(float4*)&xs[row * 132 + col] = v;
    }
    __syncthreads();

    if (tid < 192) {
        const int ut = tid / 12, yt = tid - ut * 12;  // 16 u-tiles x 12 y-tiles
        const int u0 = ut << 2, y0 = yt << 1;         // 4u x 2y register tile
        float ar[4][2] = {}, ai[4][2] = {};
        for (int v = 0; v < 128; v += 4) {
            float4 xv[4], c4[2], s4[2];
            #pragma unroll
            for (int i = 0; i < 4; ++i) xv[i] = *(const float4*)&xs[(u0 + i) * 132 + v];
            #pragma unroll
            for (int j = 0; j < 2; ++j) {
                c4[j] = *(const float4*)&tcs[(y0 + j) * 132 + v];
                s4[j] = *(const float4*)&tss[(y0 + j) * 132 + v];
            }
            #pragma unroll
            for (int i = 0; i < 4; ++i)
                #pragma unroll
                for (int j = 0; j < 2; ++j) {
                    ar[i][j] += xv[i].x * c4[j].x + xv[i].y * c4[j].y
                              + xv[i].z * c4[j].z + xv[i].w * c4[j].w;
                    ai[i][j] -= xv[i].x * s4[j].x + xv[i].y * s4[j].y
                              + xv[i].z * s4[j].z + xv[i].w * s4[j].w;
                }
        }
        const size_t tb = (size_t)bc * 3072 + uh + u0;
        #pragma unroll
        for (int j = 0; j < 2; ++j)
            #pragma unroll
            for (int i = 0; i < 4; ++i) {
                TrB[tb + (size_t)(y0 + j) * 128 + i] = __float2bfloat16(ar[i][j]);
                TiB[tb + (size_t)(y0 + j) * 128 + i] = __float2bfloat16(ai[i][j]);
            }
    }
}

// ---------------------------------------------------------------------------
// k_fft_h: forward DFT along H.  X[x,y] = sum_u T[y][u] e^{-2pi i u x/128}
// Block = bc.  X layout [x*24+y][bc].
// ---------------------------------------------------------------------------
__global__ __launch_bounds__(256) void k_fft_h(const BF* __restrict__ TrB,
                                               const BF* __restrict__ TiB,
                                               BF* __restrict__ XrB,
                                               BF* __restrict__ XiB) {
    __shared__ __align__(16) float tcs[24 * 132], tss[24 * 132];
    __shared__ __align__(16) float Trs[24 * 132], Tis[24 * 132];
    const int tid = threadIdx.x;
    const int bc  = blockIdx.x;

    for (int i = tid; i < 3072; i += 256) {
        int m = i >> 7, a = i & 127;
        int r = (a * m) & 127;
        float th = (float)r * 0.04908738521234052f;
        float s, c; __sincosf(th, &s, &c);
        tcs[m * 132 + a] = c;
        tss[m * 132 + a] = s;
    }
    for (int i = tid; i < 3072; i += 256) {
        int y = i >> 7, u = i & 127;
        Trs[y * 132 + u] = bf2f(TrB[(size_t)bc * 3072 + i]);
        Tis[y * 132 + u] = bf2f(TiB[(size_t)bc * 3072 + i]);
    }
    __syncthreads();

    if (tid < 144) {
        const int xt = tid / 12, yt = tid - xt * 12;
        const int x0 = xt << 1, y0 = yt << 1;
        float zr[2][2] = {}, zi[2][2] = {};
        for (int u = 0; u < 128; u += 4) {
            float4 t4[2], q4[2], c4[2], s4[2];
            #pragma unroll
            for (int j = 0; j < 2; ++j) {
                t4[j] = *(const float4*)&Trs[(y0 + j) * 132 + u];
                q4[j] = *(const float4*)&Tis[(y0 + j) * 132 + u];
            }
            #pragma unroll
            for (int i = 0; i < 2; ++i) {
                c4[i] = *(const float4*)&tcs[(x0 + i) * 132 + u];
                s4[i] = *(const float4*)&tss[(x0 + i) * 132 + u];
            }
            #pragma unroll
            for (int i = 0; i < 2; ++i)
                #pragma unroll
                for (int j = 0; j < 2; ++j) {
                    zr[i][j] += t4[j].x * c4[i].x + q4[j].x * s4[i].x
                              + t4[j].y * c4[i].y + q4[j].y * s4[i].y
                              + t4[j].z * c4[i].z + q4[j].z * s4[i].z
                              + t4[j].w * c4[i].w + q4[j].w * s4[i].w;
                    zi[i][j] += q4[j].x * c4[i].x - t4[j].x * s4[i].x
                              + q4[j].y * c4[i].y - t4[j].y * s4[i].y
                              + q4[j].z * c4[i].z - t4[j].z * s4[i].z
                              + q4[j].w * c4[i].w - t4[j].w * s4[i].w;
                }
        }
        #pragma unroll
        for (int i = 0; i < 2; ++i)
            #pragma unroll
            for (int j = 0; j < 2; ++j) {
                int xy = (x0 + i) * 24 + (y0 + j);
                XrB[(size_t)xy * 1024 + bc] = __float2bfloat16(zr[i][j]);
                XiB[(size_t)xy * 1024 + bc] = __float2bfloat16(zi[i][j]);
            }
    }
}

// ---------------------------------------------------------------------------
// k_mix: per-mode complex channel mix.  S[b,o] = sum_c X[b,c] * (wr + i wi)[c,o]
// Block = xy (576).  Weights fp32 direct.  S layout [b*64+o][xy].
// ---------------------------------------------------------------------------
__global__ __launch_bounds__(256) void k_mix(const float* __restrict__ wr_g,
                                             const float* __restrict__ wi_g,
                                             const BF* __restrict__ XrB,
                                             const BF* __restrict__ XiB,
                                             BF* __restrict__ SrB,
                                             BF* __restrict__ SiB) {
    __shared__ __align__(16) float Wr[4096], Wi[4096];   // [c][o]
    __shared__ __align__(16) float Xr[16 * 68], Xi[16 * 68];
    const int tid = threadIdx.x;
    const int xy  = blockIdx.x;

    const float4* wr4 = (const float4*)(wr_g + ((size_t)xy << 12));
    const float4* wi4 = (const float4*)(wi_g + ((size_t)xy << 12));
    for (int i = tid; i < 1024; i += 256) {
        *(float4*)&Wr[i << 2] = wr4[i];
        *(float4*)&Wi[i << 2] = wi4[i];
    }
    for (int i = tid; i < 1024; i += 256) {
        int b = i >> 6, c = i & 63;
        Xr[b * 68 + c] = bf2f(XrB[((size_t)xy << 10) + i]);
        Xi[b * 68 + c] = bf2f(XiB[((size_t)xy << 10) + i]);
    }
    __syncthreads();

    const int b  = tid >> 4;
    const int o0 = (tid & 15) << 2;
    float4 sr = {0.f, 0.f, 0.f, 0.f}, si = {0.f, 0.f, 0.f, 0.f};
    const float* xrp = Xr + b * 68;
    const float* xip = Xi + b * 68;
    for (int c = 0; c < 64; ++c) {
        float ar = xrp[c], ac = xip[c];
        float4 w_r = *(const float4*)&Wr[(c << 6) + o0];
        float4 w_i = *(const float4*)&Wi[(c << 6) + o0];
        sr.x += ar * w_r.x - ac * w_i.x;  si.x += ar * w_i.x + ac * w_r.x;
        sr.y += ar * w_r.y - ac * w_i.y;  si.y += ar * w_i.y + ac * w_r.y;
        sr.z += ar * w_r.z - ac * w_i.z;  si.z += ar * w_i.z + ac * w_r.z;
        sr.w += ar * w_r.w - ac * w_i.w;  si.w += ar * w_i.w + ac * w_r.w;
    }
    size_t base = (size_t)((b << 6) + o0) * 576 + xy;
    SrB[base]        = __float2bfloat16(sr.x);  SiB[base]        = __float2bfloat16(si.x);
    SrB[base + 576]  = __float2bfloat16(sr.y);  SiB[base + 576]  = __float2bfloat16(si.y);
    SrB[base + 1152] = __float2bfloat16(sr.z);  SiB[base + 1152] = __float2bfloat16(si.z);
    SrB[base + 1728] = __float2bfloat16(sr.w);  SiB[base + 1728] = __float2bfloat16(si.w);
}

// ---------------------------------------------------------------------------
// k_invP: inverse H-transform.  P[u,y] = sum_x S[x,y] e^{+2pi i u x/128},
// folding hermitian weight (y=0: x1, Im:=0; y>0: x2) and the 1/16384 norm.
// Block = bo (1024).  P layout [bo][u][y].
// ---------------------------------------------------------------------------
__global__ __launch_bounds__(256) void k_invP(const BF* __restrict__ SrB,
                                              const BF* __restrict__ SiB,
                                              BF* __restrict__ PrB,
                                              BF* __restrict__ PiB) {
    __shared__ __align__(16) float Srs[24 * 28], Sis[24 * 28];   // [y][x]
    __shared__ __align__(16) float tcs[24 * 132], tss[24 * 132]; // [m][a]
    const int tid = threadIdx.x;
    const int bo  = blockIdx.x;

    for (int i = tid; i < 3072; i += 256) {
        int m = i >> 7, a = i & 127;
        int r = (a * m) & 127;
        float th = (float)r * 0.04908738521234052f;
        float s, c; __sincosf(th, &s, &c);
        tcs[m * 132 + a] = c;
        tss[m * 132 + a] = s;
    }
    for (int i = tid; i < 576; i += 256) {
        int xx = i / 24, yy = i - xx * 24;
        Srs[yy * 28 + xx] = bf2f(SrB[(size_t)bo * 576 + i]);
        Sis[yy * 28 + xx] = bf2f(SiB[(size_t)bo * 576 + i]);
    }
    __syncthreads();

    const int u  = tid & 127;
    const int yh = (tid >> 7) * 12;
    float tcu[24], tsu[24];
    #pragma unroll
    for (int xx = 0; xx < 24; ++xx) {
        tcu[xx] = tcs[xx * 132 + u];
        tsu[xx] = tss[xx * 132 + u];
    }
    const float inv = 6.103515625e-05f;   // 1/16384
    BF* prp = PrB + (size_t)bo * 3072 + (size_t)u * 24;
    BF* pip = PiB + (size_t)bo * 3072 + (size_t)u * 24;
    for (int jy = 0; jy < 12; ++jy) {
        int y = yh + jy;
        float pr = 0.f, pi = 0.f;
        #pragma unroll
        for (int xq = 0; xq < 6; ++xq) {
            int x0 = xq << 2;
            float4 s4 = *(const float4*)&Srs[y * 28 + x0];
            float4 z4 = *(const float4*)&Sis[y * 28 + x0];
            pr += s4.x * tcu[x0]     - z4.x * tsu[x0]
                + s4.y * tcu[x0 + 1] - z4.y * tsu[x0 + 1]
                + s4.z * tcu[x0 + 2] - z4.z * tsu[x0 + 2]
                + s4.w * tcu[x0 + 3] - z4.w * tsu[x0 + 3];
            pi += z4.x * tcu[x0]     + s4.x * tsu[x0]
                + z4.y * tcu[x0 + 1] + s4.y * tsu[x0 + 1]
                + z4.z * tcu[x0 + 2] + s4.z * tsu[x0 + 2]
                + z4.w * tcu[x0 + 3] + s4.w * tsu[x0 + 3];
        }
        if (y == 0) {
            prp[0] = __float2bfloat16(pr * inv);
            pip[0] = __float2bfloat16(0.f);
        } else {
            prp[y] = __float2bfloat16(2.f * inv * pr);
            pip[y] = __float2bfloat16(2.f * inv * pi);
        }
    }
}

// ---------------------------------------------------------------------------
// k_fused (MFMA, no LDS aliasing): inverse W-transform + skip + GELU + MLP +
// soft-gate.  Block = (b, u): 2048 blocks, 256 threads = 4 waves; wave wv
// owns pixel rows v in [wv*32, wv*32+32).  All GEMMs mfma_f32_16x16x32_bf16.
//   acc  = TW(v x 48pad64) @ P^T(48pad64 x 64o)  [twiddles in registers]
//        + Xrow(v x 64c)   @ wsk^T(64c x 64o)    [A-frags direct from global x]
//   h1   = gelu(acc)    (fp32 regs for gate; bf16 copy to H1 LDS)
//   z    = gelu(H1 @ w1^T + b1)                  (bf16 Zl LDS)
//   out  = Z @ w2^T + b2 + gate*h1               (fp32 stores)
// LDS (disjoint, write-once): Plds[64][72] 9.2KB, H1[128][72] 18.4KB,
// Zl[128][40] 10.2KB = 37.9KB total, 4 blocks/CU.
// ---------------------------------------------------------------------------
__global__ __launch_bounds__(256) void k_fused(const float* __restrict__ x,
                                               const BF* __restrict__ PrB,
                                               const BF* __restrict__ PiB,
                                               const float* __restrict__ wsk,
                                               const float* __restrict__ w1,
                                               const float* __restrict__ b1,
                                               const float* __restrict__ w2,
                                               const float* __restrict__ b2,
                                               const float* __restrict__ gt,
                                               float* __restrict__ out) {
    __shared__ __align__(16) short Plds[64 * 72];    // P^T [o][k], k=0..23 Re, 24..47 Im, 48..63 zero
    __shared__ __align__(16) short H1s[128 * 72];    // h1 bf16 [v][o]
    __shared__ __align__(16) short Zls[128 * 40];    // z  bf16 [v][k']

    const int tid  = threadIdx.x;
    const int b    = blockIdx.x >> 7;
    const int u    = blockIdx.x & 127;
    const int lane = tid & 63;
    const int wv   = tid >> 6;     // wave id: pixel rows [wv*32, wv*32+32)
    const int lr   = lane & 15;    // A-row / B-col within 16-tile
    const int lg   = lane >> 4;    // k-group (8 elems each)

    // ---- stage P^T (the only cross-wave-shared LDS data)
    {
        const size_t pb = (size_t)(b * 64) * 3072 + (size_t)u * 24;
        for (int i = tid; i < 1536; i += 256) {
            int o = i / 24, y = i - o * 24;
            size_t g = pb + (size_t)o * 3072 + y;
            Plds[o * 72 + y]      = *(const short*)&PrB[g];   // bf16 bits pass-through
            Plds[o * 72 + 24 + y] = *(const short*)&PiB[g];
        }
        for (int i = tid; i < 1024; i += 256)                 // zero K-pad
            Plds[(i >> 4) * 72 + 48 + (i & 15)] = 0;
    }

    // ---- skip-GEMM A-frags direct from global x (no LDS staging)
    // A[row=v][k=c]: ax[m][s][j] = x[b][c=s*32+lg*8+j][u][v=wv*32+m*16+lr]
    s8b ax[2][2];
    {
        const float* xb = x + (size_t)(b * 64) * 16384 + (size_t)u * 128;
        #pragma unroll
        for (int m = 0; m < 2; ++m) {
            const int v = wv * 32 + m * 16 + lr;
            #pragma unroll
            for (int s = 0; s < 2; ++s)
                #pragma unroll
                for (int j = 0; j < 8; ++j)
                    ax[m][s][j] = f2bs(xb[(size_t)(s * 32 + lg * 8 + j) * 16384 + v]);
        }
    }

    // ---- twiddle A-frags in registers (32 sincos/thread)
    // spec[v][o] = sum_y Pr[o][y]*cos(th(v,y)) - Pi[o][y]*sin(th(v,y))
    s8b atw[2][2];
    #pragma unroll
    for (int m = 0; m < 2; ++m) {
        const int v = wv * 32 + m * 16 + lr;
        #pragma unroll
        for (int s = 0; s < 2; ++s) {
            #pragma unroll
            for (int j = 0; j < 8; ++j) {
                const int k = s * 32 + lg * 8 + j;
                float val = 0.f;
                if (k < 48) {
                    int y = (k < 24) ? k : k - 24;
                    int r = (v * y) & 127;
                    float sn, cs;
                    __sincosf((float)r * 0.04908738521234052f, &sn, &cs);
                    val = (k < 24) ? cs : -sn;
                }
                atw[m][s][j] = f2bs(val);
            }
        }
    }
    __syncthreads();   // Plds staged

    // ---- GEMM 1+2: spectral + skip into one fp32 accumulator (same D tiling)
    f32x4 acc[2][4];
    #pragma unroll
    for (int m = 0; m < 2; ++m)
        #pragma unroll
        for (int n = 0; n < 4; ++n)
            #pragma unroll
            for (int r = 0; r < 4; ++r) acc[m][n][r] = 0.f;

    #pragma unroll
    for (int s = 0; s < 2; ++s) {
        #pragma unroll
        for (int n = 0; n < 4; ++n) {
            s8b bfr = *(const s8b*)&Plds[(n * 16 + lr) * 72 + s * 32 + lg * 8];
            #pragma unroll
            for (int m = 0; m < 2; ++m)
                acc[m][n] = __builtin_amdgcn_mfma_f32_16x16x32_bf16(atw[m][s], bfr, acc[m][n], 0, 0, 0);
        }
    }
    #pragma unroll
    for (int s = 0; s < 2; ++s) {
        #pragma unroll
        for (int n = 0; n < 4; ++n) {
            s8b bfr = ld8f(wsk + (n * 16 + lr) * 64 + s * 32 + lg * 8);
            #pragma unroll
            for (int m = 0; m < 2; ++m)
                acc[m][n] = __builtin_amdgcn_mfma_f32_16x16x32_bf16(ax[m][s], bfr, acc[m][n], 0, 0, 0);
        }
    }

    // ---- h1 = gelu(acc): fp32 in regs (for gate term), bf16 copy to H1 LDS
    // D layout: row v = wv*32 + m*16 + lg*4 + r, col o = n*16 + lr
    f32x4 h1r[2][4];
    #pragma unroll
    for (int m = 0; m < 2; ++m)
        #pragma unroll
        for (int n = 0; n < 4; ++n)
            #pragma unroll
            for (int r = 0; r < 4; ++r) {
                float h = geluf(acc[m][n][r]);
                h1r[m][n][r] = h;
                H1s[(wv * 32 + m * 16 + lg * 4 + r) * 72 + n * 16 + lr] = f2bs(h);
            }
    __syncthreads();   // H1 complete

    // ---- fc1: z = gelu(H1 @ w1^T + b1), N=32 (2 tiles), K=64
    f32x4 zac[2][2];
    #pragma unroll
    for (int m = 0; m < 2; ++m)
        #pragma unroll
        for (int n = 0; n < 2; ++n)
            #pragma unroll
            for (int r = 0; r < 4; ++r) zac[m][n][r] = 0.f;
    #pragma unroll
    for (int s = 0; s < 2; ++s) {
        s8b ah[2];
        #pragma unroll
        for (int m = 0; m < 2; ++m)
            ah[m] = *(const s8b*)&H1s[(wv * 32 + m * 16 + lr) * 72 + s * 32 + lg * 8];
        #pragma unroll
        for (int n = 0; n < 2; ++n) {
            s8b bfr = ld8f(w1 + (n * 16 + lr) * 64 + s * 32 + lg * 8);
            #pragma unroll
            for (int m = 0; m < 2; ++m)
                zac[m][n] = __builtin_amdgcn_mfma_f32_16x16x32_bf16(ah[m], bfr, zac[m][n], 0, 0, 0);
        }
    }
    #pragma unroll
    for (int n = 0; n < 2; ++n) {
        const float bb = b1[n * 16 + lr];
        #pragma unroll
        for (int m = 0; m < 2; ++m)
            #pragma unroll
            for (int r = 0; r < 4; ++r)
                Zls[(wv * 32 + m * 16 + lg * 4 + r) * 40 + n * 16 + lr] =
                    f2bs(geluf(zac[m][n][r] + bb));
    }
    __syncthreads();   // Zl complete

    // ---- fc2: out = Z @ w2^T + b2 + gate*h1,  N=64 (4 tiles), K=32 (1 step)
    f32x4 oac[2][4];
    #pragma unroll
    for (int m = 0; m < 2; ++m)
        #pragma unroll
        for (int n = 0; n < 4; ++n)
            #pragma unroll
            for (int r = 0; r < 4; ++r) oac[m][n][r] = 0.f;
    s8b az[2];
    #pragma unroll
    for (int m = 0; m < 2; ++m)
        az[m] = *(const s8b*)&Zls[(wv * 32 + m * 16 + lr) * 40 + lg * 8];
    #pragma unroll
    for (int n = 0; n < 4; ++n) {
        s8b bfr = ld8f(w2 + (n * 16 + lr) * 32 + lg * 8);
        #pragma unroll
        for (int m = 0; m < 2; ++m)
            oac[m][n] = __builtin_amdgcn_mfma_f32_16x16x32_bf16(az[m], bfr, oac[m][n], 0, 0, 0);
    }

    float* ob = out + ((size_t)(b * 64) * 128 + u) * 128;
    #pragma unroll
    for (int n = 0; n < 4; ++n) {
        const int o = n * 16 + lr;
        const float b2v = b2[o];
        const float gv  = gt[o];
        #pragma unroll
        for (int m = 0; m < 2; ++m)
            #pragma unroll
            for (int r = 0; r < 4; ++r) {
                int v = wv * 32 + m * 16 + lg * 4 + r;
                ob[(size_t)o * 16384 + v] = oac[m][n][r] + b2v + gv * h1r[m][n][r];
            }
    }
}

// ---------------------------------------------------------------------------
extern "C" void kernel_launch(void* const* d_in, const int* in_sizes, int n_in,
                              void* d_out, int out_size, void* d_ws, size_t ws_size,
                              hipStream_t stream) {
    (void)in_sizes; (void)n_in; (void)out_size; (void)ws_size;
    const float* x   = (const float*)d_in[0];
    const float* wr  = (const float*)d_in[1];
    const float* wi  = (const float*)d_in[2];
    const float* wsk = (const float*)d_in[3];
    const float* w1  = (const float*)d_in[4];
    const float* b1  = (const float*)d_in[5];
    const float* w2  = (const float*)d_in[6];
    const float* b2  = (const float*)d_in[7];
    const float* gt  = (const float*)d_in[8];

    BF* wsB = (BF*)d_ws;
    BF* Tr  = wsB;                 // [0, 3145728)
    BF* Ti  = wsB + 3145728;       // [3145728, 6291456)
    BF* Xr  = wsB + 6291456;       // [6291456, 6881280)
    BF* Xi  = wsB + 6881280;       // [6881280, 7471104)
    BF* Sr  = wsB;                 // aliases Tr (T dead after k_fft_h)
    BF* Si  = wsB + 589824;
    BF* Pr  = wsB + 1179648;       // [1179648, 4325376) aliases Tr/Ti (dead)
    BF* Pi  = wsB + 4325376;       // [4325376, 7471104) aliases Ti/X (X dead)
    // peak footprint: 7471104 bf16 = 14.94 MB

    hipLaunchKernelGGL(k_fft_w, dim3(2048), dim3(256), 0, stream, x, Tr, Ti);
    hipLaunchKernelGGL(k_fft_h, dim3(1024), dim3(256), 0, stream, Tr, Ti, Xr, Xi);
    hipLaunchKernelGGL(k_mix,   dim3(576),  dim3(256), 0, stream, wr, wi, Xr, Xi, Sr, Si);
    hipLaunchKernelGGL(k_invP,  dim3(1024), dim3(256), 0, stream, Sr, Si, Pr, Pi);
    hipLaunchKernelGGL(k_fused, dim3(2048), dim3(256), 0, stream,
                       x, Pr, Pi, wsk, w1, b1, w2, b2, gt, (float*)d_out);
}

// Round 3
// 239.437 us; speedup vs baseline: 2.2448x; 1.2283x over previous
//
#include <hip/hip_runtime.h>
#include <hip/hip_bf16.h>

#define BF __hip_bfloat16

// B=16, C=64, H=128, W=128, MX=MY=24, HIDDEN=32
// fp32 in/out; intermediates bf16.
//
// Workspace (bf16 units):
//   Xr [6291456,6881280)  [xy][bc]          (dead after k_mix)
//   Xi [6881280,7471104)
//   Sr [0,589824)         [bo][xy]
//   Si [589824,1179648)
//   Pr [1179648,4325376)  [bo][u][y]
//   Pi [4325376,7471104)  (aliases X region; X dead after k_mix)
//
// R7 (passed, 294 us): k_fused on MFMA, no LDS aliasing. k_fused = 77 us;
// upstream 4 kernels = 216 us, now dominant.
// R8: k_fft_w + k_fft_h replaced by ONE MFMA kernel k_fwd (per-bc block):
//   GEMM1 (M=128u x N=48[Tr|Ti] x K=128v), A direct from global x,
//   B = twiddle LDS; D -> LDS Tl.  GEMM2 (M=24y x N=48[Xr|Xi] x K=256),
//   A = Tl, B = twiddle2 LDS; D -> X global ([xy][bc], same as before).
//   Kills the 24 MB T round-trip + ~600M dependent VALU FMAs.
// k_mix / k_invP / k_fused byte-identical to R7.

typedef __attribute__((ext_vector_type(8))) short s8b;    // 8 bf16 (4 VGPRs)
typedef __attribute__((ext_vector_type(4))) float f32x4;  // MFMA acc

__device__ __forceinline__ float geluf(float v) {
    return 0.5f * v * (1.0f + erff(v * 0.7071067811865476f));
}
__device__ __forceinline__ float bf2f(BF v) { return __bfloat162float(v); }
__device__ __forceinline__ short f2bs(float f) {
    union { BF h; short s; } u; u.h = __float2bfloat16(f); return u.s;
}
// build bf16x8 B-fragment from 8 consecutive fp32 (row-major [col][k] weights)
__device__ __forceinline__ s8b ld8f(const float* __restrict__ p) {
    float4 a = *(const float4*)p;
    float4 b = *(const float4*)(p + 4);
    s8b r;
    r[0] = f2bs(a.x); r[1] = f2bs(a.y); r[2] = f2bs(a.z); r[3] = f2bs(a.w);
    r[4] = f2bs(b.x); r[5] = f2bs(b.y); r[6] = f2bs(b.z); r[7] = f2bs(b.w);
    return r;
}

// ---------------------------------------------------------------------------
// k_fwd: both forward DFTs for one bc, on MFMA.
//   T[y'][u] (y'<24: Tr[y], y'>=24: Ti[y-24]):
//     Tr[y][u] = sum_v x[u][v] cos(2pi v y/128); Ti = -sum x sin.
//   X[x,y]: Xr = sum_u Tr[y][u] cos(2pi u x/128) + Ti sin;
//           Xi = sum_u Ti cos - Tr sin.
// Block = bc (1024 blocks, 256 thr = 4 waves).
// LDS: B1[48][136] GEMM1 twiddle, B2[48][264] GEMM2 twiddle, Tl[48][136].
// ---------------------------------------------------------------------------
__global__ __launch_bounds__(256) void k_fwd(const float* __restrict__ x,
                                             BF* __restrict__ XrB,
                                             BF* __restrict__ XiB) {
    __shared__ __align__(16) short B1[48 * 136];
    __shared__ __align__(16) short B2[48 * 264];
    __shared__ __align__(16) short Tl[48 * 136];

    const int tid  = threadIdx.x;
    const int bc   = blockIdx.x;
    const int lane = tid & 63;
    const int wv   = tid >> 6;
    const int lr   = lane & 15;
    const int lg   = lane >> 4;

    // twiddle fills (each i -> one sincos, 2 or 4 table entries)
    for (int i = tid; i < 3072; i += 256) {
        int y = i >> 7, v = i & 127;
        int r = (v * y) & 127;
        float s, c; __sincosf((float)r * 0.04908738521234052f, &s, &c);
        B1[y * 136 + v]        = f2bs(c);
        B1[(y + 24) * 136 + v] = f2bs(-s);
    }
    for (int i = tid; i < 3072; i += 256) {
        int xx = i >> 7, u = i & 127;
        int r = (u * xx) & 127;
        float s, c; __sincosf((float)r * 0.04908738521234052f, &s, &c);
        B2[xx * 264 + u]              = f2bs(c);
        B2[xx * 264 + 128 + u]        = f2bs(s);
        B2[(xx + 24) * 264 + u]       = f2bs(-s);
        B2[(xx + 24) * 264 + 128 + u] = f2bs(c);
    }
    __syncthreads();

    // ---- GEMM1: M=128 (u, wave wv rows wv*32..+32), N=48, K=128.
    {
        const float* xb = x + ((size_t)bc << 14);
        s8b af[2][4];
        #pragma unroll
        for (int m = 0; m < 2; ++m) {
            const int u = wv * 32 + m * 16 + lr;
            #pragma unroll
            for (int s = 0; s < 4; ++s)
                af[m][s] = ld8f(xb + (size_t)u * 128 + s * 32 + lg * 8);
        }
        f32x4 acc[2][3];
        #pragma unroll
        for (int m = 0; m < 2; ++m)
            #pragma unroll
            for (int n = 0; n < 3; ++n)
                #pragma unroll
                for (int r = 0; r < 4; ++r) acc[m][n][r] = 0.f;
        #pragma unroll
        for (int s = 0; s < 4; ++s)
            #pragma unroll
            for (int n = 0; n < 3; ++n) {
                s8b bfr = *(const s8b*)&B1[(n * 16 + lr) * 136 + s * 32 + lg * 8];
                #pragma unroll
                for (int m = 0; m < 2; ++m)
                    acc[m][n] = __builtin_amdgcn_mfma_f32_16x16x32_bf16(af[m][s], bfr, acc[m][n], 0, 0, 0);
            }
        // D -> Tl[y'][u]: col y' = n*16+lr, rows u = wv*32+m*16+lg*4+r (4 contiguous)
        #pragma unroll
        for (int m = 0; m < 2; ++m) {
            const int u0 = wv * 32 + m * 16 + lg * 4;
            #pragma unroll
            for (int n = 0; n < 3; ++n) {
                short4 t;
                t.x = f2bs(acc[m][n][0]); t.y = f2bs(acc[m][n][1]);
                t.z = f2bs(acc[m][n][2]); t.w = f2bs(acc[m][n][3]);
                *(short4*)&Tl[(n * 16 + lr) * 136 + u0] = t;
            }
        }
    }
    __syncthreads();

    // ---- GEMM2: M=24 (y, pad 32 -> 2 m-tiles), N=48, K=256 (Tr 0..127, Ti 128..255).
    // 6 tile-jobs over 4 waves.
    for (int j = wv; j < 6; j += 4) {
        const int m = j / 3, n = j % 3;
        const int y  = m * 16 + lr;
        const int r1 = (y < 24) ? y      : 0;   // Tr row (clamped junk for pad rows)
        const int r2 = (y < 24) ? y + 24 : 0;   // Ti row
        f32x4 acc = {0.f, 0.f, 0.f, 0.f};
        #pragma unroll
        for (int s = 0; s < 8; ++s) {
            s8b a = *(const s8b*)&Tl[((s < 4) ? r1 : r2) * 136 + (s & 3) * 32 + lg * 8];
            s8b b = *(const s8b*)&B2[(n * 16 + lr) * 264 + s * 32 + lg * 8];
            acc = __builtin_amdgcn_mfma_f32_16x16x32_bf16(a, b, acc, 0, 0, 0);
        }
        const int col = n * 16 + lr;            // <24: Xr col x; >=24: Xi col x-24
        const int xc  = (col < 24) ? col : col - 24;
        BF* dst = (col < 24) ? XrB : XiB;
        #pragma unroll
        for (int r = 0; r < 4; ++r) {
            const int yo = m * 16 + lg * 4 + r;
            if (yo < 24)
                dst[(size_t)(xc * 24 + yo) * 1024 + bc] = __float2bfloat16(acc[r]);
        }
    }
}

// ---------------------------------------------------------------------------
// k_mix: per-mode complex channel mix.  S[b,o] = sum_c X[b,c] * (wr + i wi)[c,o]
// Block = xy (576).  Weights fp32 direct.  S layout [b*64+o][xy].
// ---------------------------------------------------------------------------
__global__ __launch_bounds__(256) void k_mix(const float* __restrict__ wr_g,
                                             const float* __restrict__ wi_g,
                                             const BF* __restrict__ XrB,
                                             const BF* __restrict__ XiB,
                                             BF* __restrict__ SrB,
                                             BF* __restrict__ SiB) {
    __shared__ __align__(16) float Wr[4096], Wi[4096];   // [c][o]
    __shared__ __align__(16) float Xr[16 * 68], Xi[16 * 68];
    const int tid = threadIdx.x;
    const int xy  = blockIdx.x;

    const float4* wr4 = (const float4*)(wr_g + ((size_t)xy << 12));
    const float4* wi4 = (const float4*)(wi_g + ((size_t)xy << 12));
    for (int i = tid; i < 1024; i += 256) {
        *(float4*)&Wr[i << 2] = wr4[i];
        *(float4*)&Wi[i << 2] = wi4[i];
    }
    for (int i = tid; i < 1024; i += 256) {
        int b = i >> 6, c = i & 63;
        Xr[b * 68 + c] = bf2f(XrB[((size_t)xy << 10) + i]);
        Xi[b * 68 + c] = bf2f(XiB[((size_t)xy << 10) + i]);
    }
    __syncthreads();

    const int b  = tid >> 4;
    const int o0 = (tid & 15) << 2;
    float4 sr = {0.f, 0.f, 0.f, 0.f}, si = {0.f, 0.f, 0.f, 0.f};
    const float* xrp = Xr + b * 68;
    const float* xip = Xi + b * 68;
    for (int c = 0; c < 64; ++c) {
        float ar = xrp[c], ac = xip[c];
        float4 w_r = *(const float4*)&Wr[(c << 6) + o0];
        float4 w_i = *(const float4*)&Wi[(c << 6) + o0];
        sr.x += ar * w_r.x - ac * w_i.x;  si.x += ar * w_i.x + ac * w_r.x;
        sr.y += ar * w_r.y - ac * w_i.y;  si.y += ar * w_i.y + ac * w_r.y;
        sr.z += ar * w_r.z - ac * w_i.z;  si.z += ar * w_i.z + ac * w_r.z;
        sr.w += ar * w_r.w - ac * w_i.w;  si.w += ar * w_i.w + ac * w_r.w;
    }
    size_t base = (size_t)((b << 6) + o0) * 576 + xy;
    SrB[base]        = __float2bfloat16(sr.x);  SiB[base]        = __float2bfloat16(si.x);
    SrB[base + 576]  = __float2bfloat16(sr.y);  SiB[base + 576]  = __float2bfloat16(si.y);
    SrB[base + 1152] = __float2bfloat16(sr.z);  SiB[base + 1152] = __float2bfloat16(si.z);
    SrB[base + 1728] = __float2bfloat16(sr.w);  SiB[base + 1728] = __float2bfloat16(si.w);
}

// ---------------------------------------------------------------------------
// k_invP: inverse H-transform.  P[u,y] = sum_x S[x,y] e^{+2pi i u x/128},
// folding hermitian weight (y=0: x1, Im:=0; y>0: x2) and the 1/16384 norm.
// Block = bo (1024).  P layout [bo][u][y].
// ---------------------------------------------------------------------------
__global__ __launch_bounds__(256) void k_invP(const BF* __restrict__ SrB,
                                              const BF* __restrict__ SiB,
                                              BF* __restrict__ PrB,
                                              BF* __restrict__ PiB) {
    __shared__ __align__(16) float Srs[24 * 28], Sis[24 * 28];   // [y][x]
    __shared__ __align__(16) float tcs[24 * 132], tss[24 * 132]; // [m][a]
    const int tid = threadIdx.x;
    const int bo  = blockIdx.x;

    for (int i = tid; i < 3072; i += 256) {
        int m = i >> 7, a = i & 127;
        int r = (a * m) & 127;
        float th = (float)r * 0.04908738521234052f;
        float s, c; __sincosf(th, &s, &c);
        tcs[m * 132 + a] = c;
        tss[m * 132 + a] = s;
    }
    for (int i = tid; i < 576; i += 256) {
        int xx = i / 24, yy = i - xx * 24;
        Srs[yy * 28 + xx] = bf2f(SrB[(size_t)bo * 576 + i]);
        Sis[yy * 28 + xx] = bf2f(SiB[(size_t)bo * 576 + i]);
    }
    __syncthreads();

    const int u  = tid & 127;
    const int yh = (tid >> 7) * 12;
    float tcu[24], tsu[24];
    #pragma unroll
    for (int xx = 0; xx < 24; ++xx) {
        tcu[xx] = tcs[xx * 132 + u];
        tsu[xx] = tss[xx * 132 + u];
    }
    const float inv = 6.103515625e-05f;   // 1/16384
    BF* prp = PrB + (size_t)bo * 3072 + (size_t)u * 24;
    BF* pip = PiB + (size_t)bo * 3072 + (size_t)u * 24;
    for (int jy = 0; jy < 12; ++jy) {
        int y = yh + jy;
        float pr = 0.f, pi = 0.f;
        #pragma unroll
        for (int xq = 0; xq < 6; ++xq) {
            int x0 = xq << 2;
            float4 s4 = *(const float4*)&Srs[y * 28 + x0];
            float4 z4 = *(const float4*)&Sis[y * 28 + x0];
            pr += s4.x * tcu[x0]     - z4.x * tsu[x0]
                + s4.y * tcu[x0 + 1] - z4.y * tsu[x0 + 1]
                + s4.z * tcu[x0 + 2] - z4.z * tsu[x0 + 2]
                + s4.w * tcu[x0 + 3] - z4.w * tsu[x0 + 3];
            pi += z4.x * tcu[x0]     + s4.x * tsu[x0]
                + z4.y * tcu[x0 + 1] + s4.y * tsu[x0 + 1]
                + z4.z * tcu[x0 + 2] + s4.z * tsu[x0 + 2]
                + z4.w * tcu[x0 + 3] + s4.w * tsu[x0 + 3];
        }
        if (y == 0) {
            prp[0] = __float2bfloat16(pr * inv);
            pip[0] = __float2bfloat16(0.f);
        } else {
            prp[y] = __float2bfloat16(2.f * inv * pr);
            pip[y] = __float2bfloat16(2.f * inv * pi);
        }
    }
}

// ---------------------------------------------------------------------------
// k_fused (MFMA, no LDS aliasing): inverse W-transform + skip + GELU + MLP +
// soft-gate.  Block = (b, u): 2048 blocks, 256 threads = 4 waves; wave wv
// owns pixel rows v in [wv*32, wv*32+32).  All GEMMs mfma_f32_16x16x32_bf16.
// ---------------------------------------------------------------------------
__global__ __launch_bounds__(256) void k_fused(const float* __restrict__ x,
                                               const BF* __restrict__ PrB,
                                               const BF* __restrict__ PiB,
                                               const float* __restrict__ wsk,
                                               const float* __restrict__ w1,
                                               const float* __restrict__ b1,
                                               const float* __restrict__ w2,
                                               const float* __restrict__ b2,
                                               const float* __restrict__ gt,
                                               float* __restrict__ out) {
    __shared__ __align__(16) short Plds[64 * 72];    // P^T [o][k], k=0..23 Re, 24..47 Im, 48..63 zero
    __shared__ __align__(16) short H1s[128 * 72];    // h1 bf16 [v][o]
    __shared__ __align__(16) short Zls[128 * 40];    // z  bf16 [v][k']

    const int tid  = threadIdx.x;
    const int b    = blockIdx.x >> 7;
    const int u    = blockIdx.x & 127;
    const int lane = tid & 63;
    const int wv   = tid >> 6;     // wave id: pixel rows [wv*32, wv*32+32)
    const int lr   = lane & 15;    // A-row / B-col within 16-tile
    const int lg   = lane >> 4;    // k-group (8 elems each)

    // ---- stage P^T (the only cross-wave-shared LDS data)
    {
        const size_t pb = (size_t)(b * 64) * 3072 + (size_t)u * 24;
        for (int i = tid; i < 1536; i += 256) {
            int o = i / 24, y = i - o * 24;
            size_t g = pb + (size_t)o * 3072 + y;
            Plds[o * 72 + y]      = *(const short*)&PrB[g];   // bf16 bits pass-through
            Plds[o * 72 + 24 + y] = *(const short*)&PiB[g];
        }
        for (int i = tid; i < 1024; i += 256)                 // zero K-pad
            Plds[(i >> 4) * 72 + 48 + (i & 15)] = 0;
    }

    // ---- skip-GEMM A-frags direct from global x (no LDS staging)
    s8b ax[2][2];
    {
        const float* xb = x + (size_t)(b * 64) * 16384 + (size_t)u * 128;
        #pragma unroll
        for (int m = 0; m < 2; ++m) {
            const int v = wv * 32 + m * 16 + lr;
            #pragma unroll
            for (int s = 0; s < 2; ++s)
                #pragma unroll
                for (int j = 0; j < 8; ++j)
                    ax[m][s][j] = f2bs(xb[(size_t)(s * 32 + lg * 8 + j) * 16384 + v]);
        }
    }

    // ---- twiddle A-frags in registers (32 sincos/thread)
    s8b atw[2][2];
    #pragma unroll
    for (int m = 0; m < 2; ++m) {
        const int v = wv * 32 + m * 16 + lr;
        #pragma unroll
        for (int s = 0; s < 2; ++s) {
            #pragma unroll
            for (int j = 0; j < 8; ++j) {
                const int k = s * 32 + lg * 8 + j;
                float val = 0.f;
                if (k < 48) {
                    int y = (k < 24) ? k : k - 24;
                    int r = (v * y) & 127;
                    float sn, cs;
                    __sincosf((float)r * 0.04908738521234052f, &sn, &cs);
                    val = (k < 24) ? cs : -sn;
                }
                atw[m][s][j] = f2bs(val);
            }
        }
    }
    __syncthreads();   // Plds staged

    // ---- GEMM 1+2: spectral + skip into one fp32 accumulator
    f32x4 acc[2][4];
    #pragma unroll
    for (int m = 0; m < 2; ++m)
        #pragma unroll
        for (int n = 0; n < 4; ++n)
            #pragma unroll
            for (int r = 0; r < 4; ++r) acc[m][n][r] = 0.f;

    #pragma unroll
    for (int s = 0; s < 2; ++s) {
        #pragma unroll
        for (int n = 0; n < 4; ++n) {
            s8b bfr = *(const s8b*)&Plds[(n * 16 + lr) * 72 + s * 32 + lg * 8];
            #pragma unroll
            for (int m = 0; m < 2; ++m)
                acc[m][n] = __builtin_amdgcn_mfma_f32_16x16x32_bf16(atw[m][s], bfr, acc[m][n], 0, 0, 0);
        }
    }
    #pragma unroll
    for (int s = 0; s < 2; ++s) {
        #pragma unroll
        for (int n = 0; n < 4; ++n) {
            s8b bfr = ld8f(wsk + (n * 16 + lr) * 64 + s * 32 + lg * 8);
            #pragma unroll
            for (int m = 0; m < 2; ++m)
                acc[m][n] = __builtin_amdgcn_mfma_f32_16x16x32_bf16(ax[m][s], bfr, acc[m][n], 0, 0, 0);
        }
    }

    // ---- h1 = gelu(acc): fp32 in regs (for gate term), bf16 copy to H1 LDS
    f32x4 h1r[2][4];
    #pragma unroll
    for (int m = 0; m < 2; ++m)
        #pragma unroll
        for (int n = 0; n < 4; ++n)
            #pragma unroll
            for (int r = 0; r < 4; ++r) {
                float h = geluf(acc[m][n][r]);
                h1r[m][n][r] = h;
                H1s[(wv * 32 + m * 16 + lg * 4 + r) * 72 + n * 16 + lr] = f2bs(h);
            }
    __syncthreads();   // H1 complete

    // ---- fc1: z = gelu(H1 @ w1^T + b1), N=32 (2 tiles), K=64
    f32x4 zac[2][2];
    #pragma unroll
    for (int m = 0; m < 2; ++m)
        #pragma unroll
        for (int n = 0; n < 2; ++n)
            #pragma unroll
            for (int r = 0; r < 4; ++r) zac[m][n][r] = 0.f;
    #pragma unroll
    for (int s = 0; s < 2; ++s) {
        s8b ah[2];
        #pragma unroll
        for (int m = 0; m < 2; ++m)
            ah[m] = *(const s8b*)&H1s[(wv * 32 + m * 16 + lr) * 72 + s * 32 + lg * 8];
        #pragma unroll
        for (int n = 0; n < 2; ++n) {
            s8b bfr = ld8f(w1 + (n * 16 + lr) * 64 + s * 32 + lg * 8);
            #pragma unroll
            for (int m = 0; m < 2; ++m)
                zac[m][n] = __builtin_amdgcn_mfma_f32_16x16x32_bf16(ah[m], bfr, zac[m][n], 0, 0, 0);
        }
    }
    #pragma unroll
    for (int n = 0; n < 2; ++n) {
        const float bb = b1[n * 16 + lr];
        #pragma unroll
        for (int m = 0; m < 2; ++m)
            #pragma unroll
            for (int r = 0; r < 4; ++r)
                Zls[(wv * 32 + m * 16 + lg * 4 + r) * 40 + n * 16 + lr] =
                    f2bs(geluf(zac[m][n][r] + bb));
    }
    __syncthreads();   // Zl complete

    // ---- fc2: out = Z @ w2^T + b2 + gate*h1
    f32x4 oac[2][4];
    #pragma unroll
    for (int m = 0; m < 2; ++m)
        #pragma unroll
        for (int n = 0; n < 4; ++n)
            #pragma unroll
            for (int r = 0; r < 4; ++r) oac[m][n][r] = 0.f;
    s8b az[2];
    #pragma unroll
    for (int m = 0; m < 2; ++m)
        az[m] = *(const s8b*)&Zls[(wv * 32 + m * 16 + lr) * 40 + lg * 8];
    #pragma unroll
    for (int n = 0; n < 4; ++n) {
        s8b bfr = ld8f(w2 + (n * 16 + lr) * 32 + lg * 8);
        #pragma unroll
        for (int m = 0; m < 2; ++m)
            oac[m][n] = __builtin_amdgcn_mfma_f32_16x16x32_bf16(az[m], bfr, oac[m][n], 0, 0, 0);
    }

    float* ob = out + ((size_t)(b * 64) * 128 + u) * 128;
    #pragma unroll
    for (int n = 0; n < 4; ++n) {
        const int o = n * 16 + lr;
        const float b2v = b2[o];
        const float gv  = gt[o];
        #pragma unroll
        for (int m = 0; m < 2; ++m)
            #pragma unroll
            for (int r = 0; r < 4; ++r) {
                int v = wv * 32 + m * 16 + lg * 4 + r;
                ob[(size_t)o * 16384 + v] = oac[m][n][r] + b2v + gv * h1r[m][n][r];
            }
    }
}

// ---------------------------------------------------------------------------
extern "C" void kernel_launch(void* const* d_in, const int* in_sizes, int n_in,
                              void* d_out, int out_size, void* d_ws, size_t ws_size,
                              hipStream_t stream) {
    (void)in_sizes; (void)n_in; (void)out_size; (void)ws_size;
    const float* x   = (const float*)d_in[0];
    const float* wr  = (const float*)d_in[1];
    const float* wi  = (const float*)d_in[2];
    const float* wsk = (const float*)d_in[3];
    const float* w1  = (const float*)d_in[4];
    const float* b1  = (const float*)d_in[5];
    const float* w2  = (const float*)d_in[6];
    const float* b2  = (const float*)d_in[7];
    const float* gt  = (const float*)d_in[8];

    BF* wsB = (BF*)d_ws;
    BF* Xr  = wsB + 6291456;       // [6291456, 6881280)
    BF* Xi  = wsB + 6881280;       // [6881280, 7471104)
    BF* Sr  = wsB;                 // [0, 589824)
    BF* Si  = wsB + 589824;
    BF* Pr  = wsB + 1179648;       // [1179648, 4325376)
    BF* Pi  = wsB + 4325376;       // [4325376, 7471104) aliases X (X dead)
    // peak footprint: 7471104 bf16 = 14.94 MB

    hipLaunchKernelGGL(k_fwd,  dim3(1024), dim3(256), 0, stream, x, Xr, Xi);
    hipLaunchKernelGGL(k_mix,  dim3(576),  dim3(256), 0, stream, wr, wi, Xr, Xi, Sr, Si);
    hipLaunchKernelGGL(k_invP, dim3(1024), dim3(256), 0, stream, Sr, Si, Pr, Pi);
    hipLaunchKernelGGL(k_fused, dim3(2048), dim3(256), 0, stream,
                       x, Pr, Pi, wsk, w1, b1, w2, b2, gt, (float*)d_out);
}

// Round 4
// 222.660 us; speedup vs baseline: 2.4139x; 1.0753x over previous
//
#include <hip/hip_runtime.h>
#include <hip/hip_bf16.h>

#define BF __hip_bfloat16

// B=16, C=64, H=128, W=128, MX=MY=24, HIDDEN=32
// fp32 in/out; intermediates bf16.
//
// Workspace (bf16 units, peak 7471104 = 14.94 MB, unchanged):
//   gB1 [0,6144)        k_fwd GEMM1 B-table   (dead after k_fwd; S overwrites)
//   gB2 [6144,18432)    k_fwd GEMM2 B-table   (dead after k_fwd)
//   Xr  [6291456,6881280)  [xy][bc]           (dead after k_mix)
//   Xi  [6881280,7471104)
//   Sr  [0,589824)      [bo][xy]              (overwrites gB1/gB2, legal)
//   Si  [589824,1179648)
//   Pr  [1179648,4325376)  [bo][u][y]
//   Pi  [4325376,7471104)  (aliases X; X dead after k_mix)
//
// R8 (passed, 239 us): k_fwd MFMA. k_fused 77; fwd+mix+invP ~162.
// R9: (1) k_mix -> MFMA (M=16b x N=64o x K=128[Xr|Xi], weights LDS-staged
//     as Br=[Wr|-Wi], Bi=[Wi|Wr]); (2) k_invP -> MFMA (M=128u x N=48[Pr|Pi]
//     x K=48pad64, hermitian x2 + 1/16384 folded into B staging, Pi(y=0)
//     row zeroed); (3) k_fwd twiddles from global tables written by prep
//     kernel k_tw (LDS 51->13 KB, no per-block sincos); (4) k_fused gelu
//     via A&S erf polynomial (|eps|<=1.5e-7) instead of libm erff.

typedef __attribute__((ext_vector_type(8))) short s8b;    // 8 bf16 (4 VGPRs)
typedef __attribute__((ext_vector_type(4))) float f32x4;  // MFMA acc

__device__ __forceinline__ float erf_fast(float x) {
    // Abramowitz-Stegun 7.1.26, |eps| <= 1.5e-7
    float ax = fabsf(x);
    float t  = 1.0f / (1.0f + 0.3275911f * ax);
    float p  = t * (0.254829592f + t * (-0.284496736f + t * (1.421413741f
             + t * (-1.453152027f + t * 1.061405429f))));
    float r  = 1.0f - p * __expf(-ax * ax);
    return copysignf(r, x);
}
__device__ __forceinline__ float geluf(float v) {
    return 0.5f * v * (1.0f + erf_fast(v * 0.7071067811865476f));
}
__device__ __forceinline__ float bf2f(BF v) { return __bfloat162float(v); }
__device__ __forceinline__ short f2bs(float f) {
    union { BF h; short s; } u; u.h = __float2bfloat16(f); return u.s;
}
// build bf16x8 B-fragment from 8 consecutive fp32 (row-major [col][k] weights)
__device__ __forceinline__ s8b ld8f(const float* __restrict__ p) {
    float4 a = *(const float4*)p;
    float4 b = *(const float4*)(p + 4);
    s8b r;
    r[0] = f2bs(a.x); r[1] = f2bs(a.y); r[2] = f2bs(a.z); r[3] = f2bs(a.w);
    r[4] = f2bs(b.x); r[5] = f2bs(b.y); r[6] = f2bs(b.z); r[7] = f2bs(b.w);
    return r;
}

// ---------------------------------------------------------------------------
// k_tw: fill k_fwd's twiddle B-tables. gB1[48][128], gB2[48][256].
// grid 72 x 256 = 18432 elements.
// ---------------------------------------------------------------------------
__global__ __launch_bounds__(256) void k_tw(BF* __restrict__ gB1,
                                            BF* __restrict__ gB2) {
    int idx = blockIdx.x * 256 + threadIdx.x;
    if (idx < 6144) {                       // gB1[y'][v]
        int y = idx >> 7, v = idx & 127;
        int yy = (y < 24) ? y : y - 24;
        int r = (v * yy) & 127;
        float s, c; __sincosf((float)r * 0.04908738521234052f, &s, &c);
        gB1[idx] = __float2bfloat16(y < 24 ? c : -s);
    } else {                                // gB2[x'][k]: k<128 u=k; k>=128 u=k-128
        int j = idx - 6144;
        int xp = j >> 8, k = j & 255;
        int u = k & 127, half = k >> 7;
        int x = (xp < 24) ? xp : xp - 24;
        int r = (u * x) & 127;
        float s, c; __sincosf((float)r * 0.04908738521234052f, &s, &c);
        float val = (xp < 24) ? (half ? s : c) : (half ? c : -s);
        gB2[j] = __float2bfloat16(val);
    }
}

// ---------------------------------------------------------------------------
// k_fwd: both forward DFTs for one bc, on MFMA.  B-frags from global tables
// (L1/L2 resident).  LDS = Tl only (13 KB).
// ---------------------------------------------------------------------------
__global__ __launch_bounds__(256) void k_fwd(const float* __restrict__ x,
                                             const BF* __restrict__ gB1,
                                             const BF* __restrict__ gB2,
                                             BF* __restrict__ XrB,
                                             BF* __restrict__ XiB) {
    __shared__ __align__(16) short Tl[48 * 136];

    const int tid  = threadIdx.x;
    const int bc   = blockIdx.x;
    const int lane = tid & 63;
    const int wv   = tid >> 6;
    const int lr   = lane & 15;
    const int lg   = lane >> 4;

    // ---- GEMM1: M=128 (u, wave wv rows wv*32..+32), N=48, K=128.
    {
        const float* xb = x + ((size_t)bc << 14);
        s8b af[2][4];
        #pragma unroll
        for (int m = 0; m < 2; ++m) {
            const int u = wv * 32 + m * 16 + lr;
            #pragma unroll
            for (int s = 0; s < 4; ++s)
                af[m][s] = ld8f(xb + (size_t)u * 128 + s * 32 + lg * 8);
        }
        f32x4 acc[2][3];
        #pragma unroll
        for (int m = 0; m < 2; ++m)
            #pragma unroll
            for (int n = 0; n < 3; ++n)
                #pragma unroll
                for (int r = 0; r < 4; ++r) acc[m][n][r] = 0.f;
        #pragma unroll
        for (int s = 0; s < 4; ++s)
            #pragma unroll
            for (int n = 0; n < 3; ++n) {
                s8b bfr = *(const s8b*)((const short*)gB1 + (n * 16 + lr) * 128 + s * 32 + lg * 8);
                #pragma unroll
                for (int m = 0; m < 2; ++m)
                    acc[m][n] = __builtin_amdgcn_mfma_f32_16x16x32_bf16(af[m][s], bfr, acc[m][n], 0, 0, 0);
            }
        #pragma unroll
        for (int m = 0; m < 2; ++m) {
            const int u0 = wv * 32 + m * 16 + lg * 4;
            #pragma unroll
            for (int n = 0; n < 3; ++n) {
                short4 t;
                t.x = f2bs(acc[m][n][0]); t.y = f2bs(acc[m][n][1]);
                t.z = f2bs(acc[m][n][2]); t.w = f2bs(acc[m][n][3]);
                *(short4*)&Tl[(n * 16 + lr) * 136 + u0] = t;
            }
        }
    }
    __syncthreads();

    // ---- GEMM2: M=24 (y, pad 32), N=48, K=256 (Tr 0..127, Ti 128..255).
    for (int j = wv; j < 6; j += 4) {
        const int m = j / 3, n = j % 3;
        const int y  = m * 16 + lr;
        const int r1 = (y < 24) ? y      : 0;
        const int r2 = (y < 24) ? y + 24 : 0;
        f32x4 acc = {0.f, 0.f, 0.f, 0.f};
        #pragma unroll
        for (int s = 0; s < 8; ++s) {
            s8b a = *(const s8b*)&Tl[((s < 4) ? r1 : r2) * 136 + (s & 3) * 32 + lg * 8];
            s8b b = *(const s8b*)((const short*)gB2 + (n * 16 + lr) * 256 + s * 32 + lg * 8);
            acc = __builtin_amdgcn_mfma_f32_16x16x32_bf16(a, b, acc, 0, 0, 0);
        }
        const int col = n * 16 + lr;
        const int xc  = (col < 24) ? col : col - 24;
        BF* dst = (col < 24) ? XrB : XiB;
        #pragma unroll
        for (int r = 0; r < 4; ++r) {
            const int yo = m * 16 + lg * 4 + r;
            if (yo < 24)
                dst[(size_t)(xc * 24 + yo) * 1024 + bc] = __float2bfloat16(acc[r]);
        }
    }
}

// ---------------------------------------------------------------------------
// k_mix (MFMA): per-mode complex channel mix.  Block = xy (576), 256 thr.
//   S[b][o] = X[b][:] @ (W_r + i W_i),  M=16b x N=64o x K=128 ([Xr|Xi]).
//   Br = [Wr | -Wi], Bi = [Wi | Wr]  staged bf16 in LDS (write-once).
//   A-frags direct from global X (c-contiguous).
//   Wave wv owns o-tile wv for both Sr and Si.
// ---------------------------------------------------------------------------
__global__ __launch_bounds__(256) void k_mix(const float* __restrict__ wr_g,
                                             const float* __restrict__ wi_g,
                                             const BF* __restrict__ XrB,
                                             const BF* __restrict__ XiB,
                                             BF* __restrict__ SrB,
                                             BF* __restrict__ SiB) {
    __shared__ __align__(16) short Br[64 * 136], Bi[64 * 136];
    const int tid  = threadIdx.x;
    const int xy   = blockIdx.x;
    const int lane = tid & 63;
    const int wv   = tid >> 6;
    const int lr   = lane & 15;
    const int lg   = lane >> 4;

    const float* wrp = wr_g + ((size_t)xy << 12);
    const float* wip = wi_g + ((size_t)xy << 12);
    for (int i = tid; i < 4096; i += 256) {
        int c = i >> 6, o = i & 63;
        float vr = wrp[i], vi = wip[i];
        short br = f2bs(vr), bi = f2bs(vi), nbi = f2bs(-vi);
        Br[o * 136 + c]      = br;
        Br[o * 136 + 64 + c] = nbi;
        Bi[o * 136 + c]      = bi;
        Bi[o * 136 + 64 + c] = br;
    }

    // A-frags: A[b=lr][k]: k<64 Xr[c=k], k>=64 Xi[c=k-64]
    s8b az[4];
    {
        const short* xr = (const short*)XrB + ((size_t)xy << 10) + lr * 64;
        const short* xi = (const short*)XiB + ((size_t)xy << 10) + lr * 64;
        #pragma unroll
        for (int s = 0; s < 2; ++s) {
            az[s]     = *(const s8b*)(xr + s * 32 + lg * 8);
            az[s + 2] = *(const s8b*)(xi + s * 32 + lg * 8);
        }
    }
    __syncthreads();

    f32x4 ar = {0.f, 0.f, 0.f, 0.f}, ai = {0.f, 0.f, 0.f, 0.f};
    #pragma unroll
    for (int s = 0; s < 4; ++s) {
        s8b brf = *(const s8b*)&Br[(wv * 16 + lr) * 136 + s * 32 + lg * 8];
        ar = __builtin_amdgcn_mfma_f32_16x16x32_bf16(az[s], brf, ar, 0, 0, 0);
    }
    #pragma unroll
    for (int s = 0; s < 4; ++s) {
        s8b bif = *(const s8b*)&Bi[(wv * 16 + lr) * 136 + s * 32 + lg * 8];
        ai = __builtin_amdgcn_mfma_f32_16x16x32_bf16(az[s], bif, ai, 0, 0, 0);
    }

    const int o = wv * 16 + lr;
    #pragma unroll
    for (int r = 0; r < 4; ++r) {
        int b = lg * 4 + r;
        size_t base = (size_t)((b << 6) + o) * 576 + xy;
        SrB[base] = __float2bfloat16(ar[r]);
        SiB[base] = __float2bfloat16(ai[r]);
    }
}

// ---------------------------------------------------------------------------
// k_invP (MFMA): inverse H-transform.  Block = bo (1024), 256 thr, 4 waves.
//   P[u][y'] = sum_k A[u][k] B[y'][k],  M=128u x N=48([Pr y|Pi y]) x K=48pad64.
//   A[u][k<24]=cos(u*x), A[u][24..48)=sin(u*x)  (registers, bf16).
//   B[y][k<24]=sc*Sr[x][y], B[y][24..48)=-sc*Si[x][y];
//   B[24+y][k<24]=sc*Si, B[24+y][24..48)=sc*Sr; rows 24+0 zeroed (Pi[y=0]=0).
//   sc = (y==0 ? 1 : 2)/16384  (hermitian fold + norm, per-B-row => exact).
// ---------------------------------------------------------------------------
__global__ __launch_bounds__(256) void k_invP(const BF* __restrict__ SrB,
                                              const BF* __restrict__ SiB,
                                              BF* __restrict__ PrB,
                                              BF* __restrict__ PiB) {
    __shared__ __align__(16) short Bp[48 * 72];   // 6.9 KB, write-once
    const int tid  = threadIdx.x;
    const int bo   = blockIdx.x;
    const int lane = tid & 63;
    const int wv   = tid >> 6;
    const int lr   = lane & 15;
    const int lg   = lane >> 4;
    const float inv = 6.103515625e-05f;   // 1/16384

    for (int i = tid; i < 576; i += 256) {
        int x = i / 24, y = i - x * 24;
        float sr = bf2f(SrB[(size_t)bo * 576 + i]);
        float si = bf2f(SiB[(size_t)bo * 576 + i]);
        float sc = (y == 0) ? inv : 2.0f * inv;
        Bp[y * 72 + x]             = f2bs(sc * sr);
        Bp[y * 72 + 24 + x]        = f2bs(-sc * si);
        Bp[(24 + y) * 72 + x]      = f2bs((y == 0) ? 0.f : sc * si);
        Bp[(24 + y) * 72 + 24 + x] = f2bs((y == 0) ? 0.f : sc * sr);
    }
    for (int i = tid; i < 768; i += 256)          // zero K-pad [48,64)
        Bp[(i >> 4) * 72 + 48 + (i & 15)] = 0;

    // A twiddles in registers (32 sincos/thread)
    s8b a[2][2];
    #pragma unroll
    for (int m = 0; m < 2; ++m) {
        const int u = wv * 32 + m * 16 + lr;
        #pragma unroll
        for (int s = 0; s < 2; ++s) {
            #pragma unroll
            for (int j = 0; j < 8; ++j) {
                const int k = s * 32 + lg * 8 + j;
                float val = 0.f;
                if (k < 48) {
                    int x = (k < 24) ? k : k - 24;
                    int r = (u * x) & 127;
                    float sn, cs;
                    __sincosf((float)r * 0.04908738521234052f, &sn, &cs);
                    val = (k < 24) ? cs : sn;
                }
                a[m][s][j] = f2bs(val);
            }
        }
    }
    __syncthreads();

    #pragma unroll
    for (int m = 0; m < 2; ++m)
        #pragma unroll
        for (int n = 0; n < 3; ++n) {
            f32x4 acc = {0.f, 0.f, 0.f, 0.f};
            #pragma unroll
            for (int s = 0; s < 2; ++s) {
                s8b bfr = *(const s8b*)&Bp[(n * 16 + lr) * 72 + s * 32 + lg * 8];
                acc = __builtin_amdgcn_mfma_f32_16x16x32_bf16(a[m][s], bfr, acc, 0, 0, 0);
            }
            const int col = n * 16 + lr;
            BF* dst = (col < 24) ? PrB : PiB;
            const int y = (col < 24) ? col : col - 24;
            #pragma unroll
            for (int r = 0; r < 4; ++r) {
                const int u = wv * 32 + m * 16 + lg * 4 + r;
                dst[(size_t)bo * 3072 + (size_t)u * 24 + y] = __float2bfloat16(acc[r]);
            }
        }
}

// ---------------------------------------------------------------------------
// k_fused (MFMA, no LDS aliasing): inverse W-transform + skip + GELU + MLP +
// soft-gate.  Block = (b, u): 2048 blocks, 256 threads = 4 waves; wave wv
// owns pixel rows v in [wv*32, wv*32+32).  All GEMMs mfma_f32_16x16x32_bf16.
// ---------------------------------------------------------------------------
__global__ __launch_bounds__(256) void k_fused(const float* __restrict__ x,
                                               const BF* __restrict__ PrB,
                                               const BF* __restrict__ PiB,
                                               const float* __restrict__ wsk,
                                               const float* __restrict__ w1,
                                               const float* __restrict__ b1,
                                               const float* __restrict__ w2,
                                               const float* __restrict__ b2,
                                               const float* __restrict__ gt,
                                               float* __restrict__ out) {
    __shared__ __align__(16) short Plds[64 * 72];    // P^T [o][k], k=0..23 Re, 24..47 Im, 48..63 zero
    __shared__ __align__(16) short H1s[128 * 72];    // h1 bf16 [v][o]
    __shared__ __align__(16) short Zls[128 * 40];    // z  bf16 [v][k']

    const int tid  = threadIdx.x;
    const int b    = blockIdx.x >> 7;
    const int u    = blockIdx.x & 127;
    const int lane = tid & 63;
    const int wv   = tid >> 6;     // wave id: pixel rows [wv*32, wv*32+32)
    const int lr   = lane & 15;    // A-row / B-col within 16-tile
    const int lg   = lane >> 4;    // k-group (8 elems each)

    // ---- stage P^T (the only cross-wave-shared LDS data)
    {
        const size_t pb = (size_t)(b * 64) * 3072 + (size_t)u * 24;
        for (int i = tid; i < 1536; i += 256) {
            int o = i / 24, y = i - o * 24;
            size_t g = pb + (size_t)o * 3072 + y;
            Plds[o * 72 + y]      = *(const short*)&PrB[g];   // bf16 bits pass-through
            Plds[o * 72 + 24 + y] = *(const short*)&PiB[g];
        }
        for (int i = tid; i < 1024; i += 256)                 // zero K-pad
            Plds[(i >> 4) * 72 + 48 + (i & 15)] = 0;
    }

    // ---- skip-GEMM A-frags direct from global x (no LDS staging)
    s8b ax[2][2];
    {
        const float* xb = x + (size_t)(b * 64) * 16384 + (size_t)u * 128;
        #pragma unroll
        for (int m = 0; m < 2; ++m) {
            const int v = wv * 32 + m * 16 + lr;
            #pragma unroll
            for (int s = 0; s < 2; ++s)
                #pragma unroll
                for (int j = 0; j < 8; ++j)
                    ax[m][s][j] = f2bs(xb[(size_t)(s * 32 + lg * 8 + j) * 16384 + v]);
        }
    }

    // ---- twiddle A-frags in registers (32 sincos/thread)
    s8b atw[2][2];
    #pragma unroll
    for (int m = 0; m < 2; ++m) {
        const int v = wv * 32 + m * 16 + lr;
        #pragma unroll
        for (int s = 0; s < 2; ++s) {
            #pragma unroll
            for (int j = 0; j < 8; ++j) {
                const int k = s * 32 + lg * 8 + j;
                float val = 0.f;
                if (k < 48) {
                    int y = (k < 24) ? k : k - 24;
                    int r = (v * y) & 127;
                    float sn, cs;
                    __sincosf((float)r * 0.04908738521234052f, &sn, &cs);
                    val = (k < 24) ? cs : -sn;
                }
                atw[m][s][j] = f2bs(val);
            }
        }
    }
    __syncthreads();   // Plds staged

    // ---- GEMM 1+2: spectral + skip into one fp32 accumulator
    f32x4 acc[2][4];
    #pragma unroll
    for (int m = 0; m < 2; ++m)
        #pragma unroll
        for (int n = 0; n < 4; ++n)
            #pragma unroll
            for (int r = 0; r < 4; ++r) acc[m][n][r] = 0.f;

    #pragma unroll
    for (int s = 0; s < 2; ++s) {
        #pragma unroll
        for (int n = 0; n < 4; ++n) {
            s8b bfr = *(const s8b*)&Plds[(n * 16 + lr) * 72 + s * 32 + lg * 8];
            #pragma unroll
            for (int m = 0; m < 2; ++m)
                acc[m][n] = __builtin_amdgcn_mfma_f32_16x16x32_bf16(atw[m][s], bfr, acc[m][n], 0, 0, 0);
        }
    }
    #pragma unroll
    for (int s = 0; s < 2; ++s) {
        #pragma unroll
        for (int n = 0; n < 4; ++n) {
            s8b bfr = ld8f(wsk + (n * 16 + lr) * 64 + s * 32 + lg * 8);
            #pragma unroll
            for (int m = 0; m < 2; ++m)
                acc[m][n] = __builtin_amdgcn_mfma_f32_16x16x32_bf16(ax[m][s], bfr, acc[m][n], 0, 0, 0);
        }
    }

    // ---- h1 = gelu(acc): fp32 in regs (for gate term), bf16 copy to H1 LDS
    f32x4 h1r[2][4];
    #pragma unroll
    for (int m = 0; m < 2; ++m)
        #pragma unroll
        for (int n = 0; n < 4; ++n)
            #pragma unroll
            for (int r = 0; r < 4; ++r) {
                float h = geluf(acc[m][n][r]);
                h1r[m][n][r] = h;
                H1s[(wv * 32 + m * 16 + lg * 4 + r) * 72 + n * 16 + lr] = f2bs(h);
            }
    __syncthreads();   // H1 complete

    // ---- fc1: z = gelu(H1 @ w1^T + b1), N=32 (2 tiles), K=64
    f32x4 zac[2][2];
    #pragma unroll
    for (int m = 0; m < 2; ++m)
        #pragma unroll
        for (int n = 0; n < 2; ++n)
            #pragma unroll
            for (int r = 0; r < 4; ++r) zac[m][n][r] = 0.f;
    #pragma unroll
    for (int s = 0; s < 2; ++s) {
        s8b ah[2];
        #pragma unroll
        for (int m = 0; m < 2; ++m)
            ah[m] = *(const s8b*)&H1s[(wv * 32 + m * 16 + lr) * 72 + s * 32 + lg * 8];
        #pragma unroll
        for (int n = 0; n < 2; ++n) {
            s8b bfr = ld8f(w1 + (n * 16 + lr) * 64 + s * 32 + lg * 8);
            #pragma unroll
            for (int m = 0; m < 2; ++m)
                zac[m][n] = __builtin_amdgcn_mfma_f32_16x16x32_bf16(ah[m], bfr, zac[m][n], 0, 0, 0);
        }
    }
    #pragma unroll
    for (int n = 0; n < 2; ++n) {
        const float bb = b1[n * 16 + lr];
        #pragma unroll
        for (int m = 0; m < 2; ++m)
            #pragma unroll
            for (int r = 0; r < 4; ++r)
                Zls[(wv * 32 + m * 16 + lg * 4 + r) * 40 + n * 16 + lr] =
                    f2bs(geluf(zac[m][n][r] + bb));
    }
    __syncthreads();   // Zl complete

    // ---- fc2: out = Z @ w2^T + b2 + gate*h1
    f32x4 oac[2][4];
    #pragma unroll
    for (int m = 0; m < 2; ++m)
        #pragma unroll
        for (int n = 0; n < 4; ++n)
            #pragma unroll
            for (int r = 0; r < 4; ++r) oac[m][n][r] = 0.f;
    s8b az[2];
    #pragma unroll
    for (int m = 0; m < 2; ++m)
        az[m] = *(const s8b*)&Zls[(wv * 32 + m * 16 + lr) * 40 + lg * 8];
    #pragma unroll
    for (int n = 0; n < 4; ++n) {
        s8b bfr = ld8f(w2 + (n * 16 + lr) * 32 + lg * 8);
        #pragma unroll
        for (int m = 0; m < 2; ++m)
            oac[m][n] = __builtin_amdgcn_mfma_f32_16x16x32_bf16(az[m], bfr, oac[m][n], 0, 0, 0);
    }

    float* ob = out + ((size_t)(b * 64) * 128 + u) * 128;
    #pragma unroll
    for (int n = 0; n < 4; ++n) {
        const int o = n * 16 + lr;
        const float b2v = b2[o];
        const float gv  = gt[o];
        #pragma unroll
        for (int m = 0; m < 2; ++m)
            #pragma unroll
            for (int r = 0; r < 4; ++r) {
                int v = wv * 32 + m * 16 + lg * 4 + r;
                ob[(size_t)o * 16384 + v] = oac[m][n][r] + b2v + gv * h1r[m][n][r];
            }
    }
}

// ---------------------------------------------------------------------------
extern "C" void kernel_launch(void* const* d_in, const int* in_sizes, int n_in,
                              void* d_out, int out_size, void* d_ws, size_t ws_size,
                              hipStream_t stream) {
    (void)in_sizes; (void)n_in; (void)out_size; (void)ws_size;
    const float* x   = (const float*)d_in[0];
    const float* wr  = (const float*)d_in[1];
    const float* wi  = (const float*)d_in[2];
    const float* wsk = (const float*)d_in[3];
    const float* w1  = (const float*)d_in[4];
    const float* b1  = (const float*)d_in[5];
    const float* w2  = (const float*)d_in[6];
    const float* b2  = (const float*)d_in[7];
    const float* gt  = (const float*)d_in[8];

    BF* wsB = (BF*)d_ws;
    BF* gB1 = wsB;                 // [0, 6144)          dead after k_fwd
    BF* gB2 = wsB + 6144;          // [6144, 18432)      dead after k_fwd
    BF* Xr  = wsB + 6291456;       // [6291456, 6881280)
    BF* Xi  = wsB + 6881280;       // [6881280, 7471104)
    BF* Sr  = wsB;                 // [0, 589824)  overwrites gB1/gB2 (legal)
    BF* Si  = wsB + 589824;
    BF* Pr  = wsB + 1179648;       // [1179648, 4325376)
    BF* Pi  = wsB + 4325376;       // [4325376, 7471104) aliases X (X dead)
    // peak footprint: 7471104 bf16 = 14.94 MB (unchanged)

    hipLaunchKernelGGL(k_tw,   dim3(72),   dim3(256), 0, stream, gB1, gB2);
    hipLaunchKernelGGL(k_fwd,  dim3(1024), dim3(256), 0, stream, x, gB1, gB2, Xr, Xi);
    hipLaunchKernelGGL(k_mix,  dim3(576),  dim3(256), 0, stream, wr, wi, Xr, Xi, Sr, Si);
    hipLaunchKernelGGL(k_invP, dim3(1024), dim3(256), 0, stream, Sr, Si, Pr, Pi);
    hipLaunchKernelGGL(k_fused, dim3(2048), dim3(256), 0, stream,
                       x, Pr, Pi, wsk, w1, b1, w2, b2, gt, (float*)d_out);
}